// Round 5
// baseline (2407.168 us; speedup 1.0000x reference)
//
#include <hip/hip_runtime.h>
#include <cstdint>

// ---------------------------------------------------------------------------
// CrossGraphMessagePassing:
//   PAPP[p][256] = interleaved {h_prot @ att_w1[0:128], h_prot @ proj_w1[0:128]}
//   LA[l] = h_lig @ att_w1[128:256] + b1a ; LP[l] = h_lig @ proj_w1[128:256] + b1p
//   Gq[20][256]  = geo-weight rows (att/proj interleaved per lane dim-pair)
//   per edge: pre = PAPP[p]+L+geo@Wg ; logit = silu(pre_a)@w2+b2
//             w=exp(logit) (|logit|<<1 -> segment-max not needed), g=exp(-d^2/32)
//             per-ligand: num += w*g*silu(pre_p), den += w, gws += w*g
//   per lig:  agg = (num/den)@proj_w2 + (gws/den)*proj_b2 ; out = LN(h_lig+agg)
// Edges counting-sorted by ligand. k_edge: ONE WAVE PER LIGAND, Phase A
// (lane==edge: scalar geo -> LDS), Phase B (wave-wide over dims, 2 edges in
// flight, gathers prefetched 1 iter ahead and consumed at END of FMA chain,
// geo chain in packed-fp32 v_pk_fma).
// ---------------------------------------------------------------------------

typedef float f2 __attribute__((ext_vector_type(2)));

__device__ __forceinline__ float fast_rcp(float x) { return __builtin_amdgcn_rcpf(x); }
__device__ __forceinline__ float siluf(float x) { return x * fast_rcp(1.0f + __expf(-x)); }
__device__ __forceinline__ f2 mk2(float a, float b) { f2 r; r.x = a; r.y = b; return r; }
__device__ __forceinline__ f2 fma2(f2 a, f2 b, f2 c) { return __builtin_elementwise_fma(a, b, c); }
__device__ __forceinline__ f2 silu2(f2 x) {
  return mk2(x.x * fast_rcp(1.0f + __expf(-x.x)),
             x.y * fast_rcp(1.0f + __expf(-x.y)));
}

// fused: copy h_prot -> out, build Gq, histogram l_idx
__global__ __launch_bounds__(256) void k_prep(
    const float4* __restrict__ hp4, float4* __restrict__ out4, int n4,
    const float* __restrict__ att_w1, const float* __restrict__ proj_w1,
    float* __restrict__ Gq,
    const int* __restrict__ l_idx, int ne, int* __restrict__ counts) {
  int i = blockIdx.x * blockDim.x + threadIdx.x;
  int stride = gridDim.x * blockDim.x;
  for (int j = i; j < n4; j += stride) out4[j] = hp4[j];
  for (int j = i; j < 20 * 256; j += stride) {
    int k = j >> 8, r = j & 255;
    int ln = r >> 2, c = r & 3;
    int d = 2 * ln + (c & 1);
    const float* src = (c < 2) ? att_w1 : proj_w1;
    Gq[j] = src[(256 + k) * 128 + d];
  }
  for (int j = i; j < ne; j += stride) atomicAdd(&counts[l_idx[j]], 1);
}

// Tables: 8 rows/block, 256 threads (t<128 -> att col d, t>=128 -> proj col d).
// interleaved==1: write into one [row][256] table as {A0,A1,P0,P1} per dim-pair.
__global__ __launch_bounds__(256) void k_tables(
    const float* __restrict__ h, int nrows,
    const float* __restrict__ Wa, const float* __restrict__ Wp,   // 128x128 (k,d)
    const float* __restrict__ ba, const float* __restrict__ bp,   // nullable
    float* __restrict__ TA, float* __restrict__ TP, int interleaved) {
  __shared__ float hT[128 * 8];  // [k][r]
  int t = threadIdx.x;
  int row0 = blockIdx.x * 8;
  for (int i = t; i < 1024; i += 256) {
    int r = i >> 7, k = i & 127;
    int gr = row0 + r;
    hT[k * 8 + r] = (gr < nrows) ? h[gr * 128 + k] : 0.0f;
  }
  __syncthreads();
  const float* W = (t < 128) ? Wa : Wp;
  const float* bias = (t < 128) ? ba : bp;
  int d = t & 127;
  float acc[8] = {0, 0, 0, 0, 0, 0, 0, 0};
  for (int k = 0; k < 128; ++k) {
    float w = W[k * 128 + d];
    const float4* h4 = reinterpret_cast<const float4*>(&hT[k * 8]);
    float4 a = h4[0], b = h4[1];
    acc[0] += a.x * w; acc[1] += a.y * w; acc[2] += a.z * w; acc[3] += a.w * w;
    acc[4] += b.x * w; acc[5] += b.y * w; acc[6] += b.z * w; acc[7] += b.w * w;
  }
  float bv = bias ? bias[d] : 0.0f;
  if (interleaved) {
    int pos = ((d >> 1) << 2) + (d & 1) + ((t < 128) ? 0 : 2);
    #pragma unroll
    for (int r = 0; r < 8; ++r) {
      int gr = row0 + r;
      if (gr < nrows) TA[(size_t)gr * 256 + pos] = acc[r] + bv;
    }
  } else {
    float* T = (t < 128) ? TA : TP;
    #pragma unroll
    for (int r = 0; r < 8; ++r) {
      int gr = row0 + r;
      if (gr < nrows) T[(size_t)gr * 128 + d] = acc[r] + bv;
    }
  }
}

__global__ __launch_bounds__(1024) void k_scan(const int* __restrict__ counts,
                                               int* __restrict__ offsets,
                                               int* __restrict__ cursor, int n) {
  __shared__ int tsum[1024];
  int t = threadIdx.x;
  int per = (n + 1023) >> 10;
  int base = t * per;
  int s = 0;
  for (int i = 0; i < per; ++i) {
    int idx = base + i;
    if (idx < n) s += counts[idx];
  }
  tsum[t] = s;
  __syncthreads();
  for (int off = 1; off < 1024; off <<= 1) {
    int v = (t >= off) ? tsum[t - off] : 0;
    __syncthreads();
    tsum[t] += v;
    __syncthreads();
  }
  int run = (t == 0) ? 0 : tsum[t - 1];
  for (int i = 0; i < per; ++i) {
    int idx = base + i;
    if (idx < n) {
      offsets[idx] = run;
      cursor[idx] = run;
      run += counts[idx];
    }
  }
}

__global__ void k_scatter(const int* __restrict__ p_idx, const int* __restrict__ l_idx, int ne,
                          int* __restrict__ cursor, int* __restrict__ sorted_p) {
  int i = blockIdx.x * blockDim.x + threadIdx.x;
  int stride = gridDim.x * blockDim.x;
  for (; i < ne; i += stride) {
    int l = l_idx[i];
    int pos = atomicAdd(&cursor[l], 1);
    sorted_p[pos] = p_idx[i];
  }
}

// ONE WAVE PER LIGAND. 256 threads = 4 waves = 4 ligands/block. No barriers.
__global__ __launch_bounds__(256, 5) void k_edge(
    const float* __restrict__ PAPP, const float* __restrict__ Gq,
    const float* __restrict__ LA, const float* __restrict__ LP,
    const float* __restrict__ prot_pos, const float* __restrict__ lig_pos,
    const int* __restrict__ offsets, const int* __restrict__ counts,
    const int* __restrict__ sorted_p,
    const float* __restrict__ att_w2, const float* __restrict__ att_b2,
    const float* __restrict__ proj_w2, const float* __restrict__ proj_b2,
    const float* __restrict__ h_lig, const float* __restrict__ ln_g,
    const float* __restrict__ ln_b,
    float* __restrict__ out, int np_total, int nl_total) {
  __shared__ alignas(16) float geoS[4][64][24];  // [wave][edge][field]
  __shared__ alignas(16) int pS[4][64];

  int t = threadIdx.x;
  int wave = t >> 6, lane = t & 63;
  int l = blockIdx.x * 4 + wave;
  if (l >= nl_total) return;  // whole-wave exit; no barriers in kernel
  int dd = 2 * lane;

  // per-lane geo weights: 20 x float4 {Ga(dd), Ga(dd+1), Gp(dd), Gp(dd+1)}
  const float4* Gq4 = reinterpret_cast<const float4*>(Gq);
  float4 G[20];
  #pragma unroll
  for (int k = 0; k < 20; ++k) G[k] = Gq4[k * 64 + lane];

  float2 lav = *reinterpret_cast<const float2*>(&LA[(size_t)l * 128 + dd]);
  float2 lpv = *reinterpret_cast<const float2*>(&LP[(size_t)l * 128 + dd]);
  float2 wav = *reinterpret_cast<const float2*>(&att_w2[dd]);
  f2 lA2 = mk2(lav.x, lav.y);
  f2 lP2 = mk2(lpv.x, lpv.y);
  float wa0 = wav.x, wa1 = wav.y;
  float lx = lig_pos[l * 3 + 0], ly = lig_pos[l * 3 + 1], lz = lig_pos[l * 3 + 2];
  float b2 = att_b2[0];

  int start = offsets[l];
  int cnt = counts[l];
  f2 acc2 = mk2(0.0f, 0.0f);
  float den = 0.0f, gws = 0.0f;

  const float4* PAPP4 = reinterpret_cast<const float4*>(PAPP);

  for (int cbase = 0; cbase < cnt; cbase += 64) {
    int cc = min(64, cnt - cbase);
    // ---- Phase A: one edge per lane (scalar geo, native exps -> LDS) ----
    if (lane < cc) {
      int p = sorted_p[start + cbase + lane];
      float px = prot_pos[p * 3 + 0], py = prot_pos[p * 3 + 1], pz = prot_pos[p * 3 + 2];
      float dx = lx - px, dy = ly - py, dz = lz - pz;
      float d2r = dx * dx + dy * dy + dz * dz;
      float dist = sqrtf(d2r);
      float inv = fast_rcp(dist + 1e-8f);
      float rb[16];
      #pragma unroll
      for (int j = 0; j < 16; ++j) {
        float c = (8.0f / 15.0f) * (float)j;  // linspace(0, 8, 16)
        float dv = dist - c;
        rb[j] = __expf(-2.0f * dv * dv);      // gamma = 2
      }
      float4* dst = reinterpret_cast<float4*>(&geoS[wave][lane][0]);
      dst[0] = make_float4(dist, dx * inv, dy * inv, dz * inv);
      dst[1] = make_float4(rb[0], rb[1], rb[2], rb[3]);
      dst[2] = make_float4(rb[4], rb[5], rb[6], rb[7]);
      dst[3] = make_float4(rb[8], rb[9], rb[10], rb[11]);
      dst[4] = make_float4(rb[12], rb[13], rb[14], rb[15]);
      geoS[wave][lane][20] = __expf(-d2r * (1.0f / 32.0f));
      pS[wave][lane] = p;
    }
    // ---- Phase B: wave-wide, 2 edges in flight, 1-iter gather prefetch ----
    int pA0 = __builtin_amdgcn_readfirstlane(pS[wave][0]);
    int pB0 = __builtin_amdgcn_readfirstlane(pS[wave][cc > 1 ? 1 : 0]);
    float4 tvA = PAPP4[(size_t)pA0 * 64 + lane];
    float4 tvB = PAPP4[(size_t)pB0 * 64 + lane];
    for (int e = 0; e < cc; e += 2) {
      int eB = (e + 1 < cc) ? e + 1 : e;
      float maskB = (e + 1 < cc) ? 1.0f : 0.0f;
      int e2 = e + 2;
      int iA2 = (e2 < cc) ? e2 : 0;
      int iB2 = (e2 + 1 < cc) ? e2 + 1 : 0;
      int pA2 = __builtin_amdgcn_readfirstlane(pS[wave][iA2]);
      int pB2 = __builtin_amdgcn_readfirstlane(pS[wave][iB2]);
      float4 ntA = PAPP4[(size_t)pA2 * 64 + lane];   // prefetch: consumed next iter
      float4 ntB = PAPP4[(size_t)pB2 * 64 + lane];

      const float4* gA4 = reinterpret_cast<const float4*>(&geoS[wave][e][0]);
      const float4* gB4 = reinterpret_cast<const float4*>(&geoS[wave][eB][0]);
      f2 aA = lA2, vA = lP2, aB = lA2, vB = lP2;
      #pragma unroll
      for (int k4 = 0; k4 < 5; ++k4) {
        float4 qA = gA4[k4];
        float4 qB = gB4[k4];
        int k = 4 * k4;
        f2 ga, gp;
        ga = mk2(G[k].x, G[k].y);         gp = mk2(G[k].z, G[k].w);
        aA = fma2(mk2(qA.x, qA.x), ga, aA); vA = fma2(mk2(qA.x, qA.x), gp, vA);
        aB = fma2(mk2(qB.x, qB.x), ga, aB); vB = fma2(mk2(qB.x, qB.x), gp, vB);
        ga = mk2(G[k + 1].x, G[k + 1].y); gp = mk2(G[k + 1].z, G[k + 1].w);
        aA = fma2(mk2(qA.y, qA.y), ga, aA); vA = fma2(mk2(qA.y, qA.y), gp, vA);
        aB = fma2(mk2(qB.y, qB.y), ga, aB); vB = fma2(mk2(qB.y, qB.y), gp, vB);
        ga = mk2(G[k + 2].x, G[k + 2].y); gp = mk2(G[k + 2].z, G[k + 2].w);
        aA = fma2(mk2(qA.z, qA.z), ga, aA); vA = fma2(mk2(qA.z, qA.z), gp, vA);
        aB = fma2(mk2(qB.z, qB.z), ga, aB); vB = fma2(mk2(qB.z, qB.z), gp, vB);
        ga = mk2(G[k + 3].x, G[k + 3].y); gp = mk2(G[k + 3].z, G[k + 3].w);
        aA = fma2(mk2(qA.w, qA.w), ga, aA); vA = fma2(mk2(qA.w, qA.w), gp, vA);
        aB = fma2(mk2(qB.w, qB.w), ga, aB); vB = fma2(mk2(qB.w, qB.w), gp, vB);
      }
      // gathered table rows join at the END of the chain (latency hiding)
      aA = aA + mk2(tvA.x, tvA.y); vA = vA + mk2(tvA.z, tvA.w);
      aB = aB + mk2(tvB.x, tvB.y); vB = vB + mk2(tvB.z, tvB.w);

      f2 hA = silu2(aA), hB = silu2(aB);
      float partA = hA.x * wa0 + hA.y * wa1;
      float partB = hB.x * wa0 + hB.y * wa1;
      #pragma unroll
      for (int off = 32; off; off >>= 1) {
        partA += __shfl_xor(partA, off);
        partB += __shfl_xor(partB, off);
      }
      float gAv = geoS[wave][e][20];
      float gBv = geoS[wave][eB][20];
      float wAe = __expf(partA + b2);
      float wBe = __expf(partB + b2) * maskB;
      float wgA = wAe * gAv, wgB = wBe * gBv;
      f2 sA = silu2(vA), sB = silu2(vB);
      acc2 = fma2(mk2(wgA, wgA), sA, acc2);
      acc2 = fma2(mk2(wgB, wgB), sB, acc2);
      den += wAe + wBe;
      gws += wgA + wgB;
      tvA = ntA; tvB = ntB;
    }
  }

  // ---- per-wave epilogue (no barriers); reuse geoS as accumulator buffer ----
  float invd = 1.0f / (den + 1e-9f);
  float* accW = &geoS[wave][0][0];  // first 128 floats of this wave's region
  *reinterpret_cast<float2*>(&accW[dd]) = make_float2(acc2.x * invd, acc2.y * invd);
  const float2* W2_2 = reinterpret_cast<const float2*>(proj_w2);
  float agg0 = 0.0f, agg1 = 0.0f;
  #pragma unroll 4
  for (int k = 0; k < 128; k += 4) {
    float4 av = *reinterpret_cast<const float4*>(&accW[k]);
    float2 w0 = W2_2[(size_t)(k + 0) * 64 + lane];
    float2 w1 = W2_2[(size_t)(k + 1) * 64 + lane];
    float2 w2 = W2_2[(size_t)(k + 2) * 64 + lane];
    float2 w3 = W2_2[(size_t)(k + 3) * 64 + lane];
    agg0 += av.x * w0.x + av.y * w1.x + av.z * w2.x + av.w * w3.x;
    agg1 += av.x * w0.y + av.y * w1.y + av.z * w2.y + av.w * w3.y;
  }
  float gval = gws * invd;
  float2 pb2 = *reinterpret_cast<const float2*>(&proj_b2[dd]);
  float2 hl = *reinterpret_cast<const float2*>(&h_lig[(size_t)l * 128 + dd]);
  float x0 = agg0 + gval * pb2.x + hl.x;
  float x1 = agg1 + gval * pb2.y + hl.y;
  float s = x0 + x1, q = x0 * x0 + x1 * x1;
  #pragma unroll
  for (int off = 32; off; off >>= 1) {
    s += __shfl_xor(s, off);
    q += __shfl_xor(q, off);
  }
  float mu = s * (1.0f / 128.0f);
  float var = q * (1.0f / 128.0f) - mu * mu;
  float rstd = rsqrtf(var + 1e-5f);
  float2 gm = *reinterpret_cast<const float2*>(&ln_g[dd]);
  float2 bt = *reinterpret_cast<const float2*>(&ln_b[dd]);
  float2 y = make_float2((x0 - mu) * rstd * gm.x + bt.x,
                         (x1 - mu) * rstd * gm.y + bt.y);
  *reinterpret_cast<float2*>(&out[(size_t)(np_total + l) * 128 + dd]) = y;
}

extern "C" void kernel_launch(void* const* d_in, const int* in_sizes, int n_in,
                              void* d_out, int out_size, void* d_ws, size_t ws_size,
                              hipStream_t stream) {
  const float* h_prot   = (const float*)d_in[0];
  const float* h_lig    = (const float*)d_in[1];
  const float* prot_pos = (const float*)d_in[2];
  const float* lig_pos  = (const float*)d_in[3];
  const int*   edges    = (const int*)d_in[4];
  const float* att_w1   = (const float*)d_in[5];
  const float* att_b1   = (const float*)d_in[6];
  const float* att_w2   = (const float*)d_in[7];
  const float* att_b2   = (const float*)d_in[8];
  const float* proj_w1  = (const float*)d_in[9];
  const float* proj_b1  = (const float*)d_in[10];
  const float* proj_w2  = (const float*)d_in[11];
  const float* proj_b2  = (const float*)d_in[12];
  const float* ln_g     = (const float*)d_in[13];
  const float* ln_b     = (const float*)d_in[14];

  int NP = in_sizes[0] / 128;
  int NL = in_sizes[1] / 128;
  int NE = in_sizes[4] / 2;
  const int* p_idx = edges;
  const int* l_idx = edges + NE;

  float* out = (float*)d_out;

  // workspace layout
  float* PAPP = (float*)d_ws;                      // NP x 256, interleaved A/P
  float* LA = PAPP + (size_t)NP * 256;
  float* LP = LA + (size_t)NL * 128;
  float* Gq = LP + (size_t)NL * 128;               // 20 x 256
  int* counts  = (int*)(Gq + 20 * 256);
  int* offsets = counts + NL;
  int* cursor  = offsets + NL;
  int* sorted_p = cursor + NL;

  hipMemsetAsync(counts, 0, (size_t)NL * sizeof(int), stream);

  k_prep<<<2048, 256, 0, stream>>>((const float4*)h_prot, (float4*)out, NP * 128 / 4,
                                   att_w1, proj_w1, Gq, l_idx, NE, counts);

  k_tables<<<(NP + 7) / 8, 256, 0, stream>>>(h_prot, NP, att_w1, proj_w1,
                                             nullptr, nullptr, PAPP, nullptr, 1);
  k_tables<<<(NL + 7) / 8, 256, 0, stream>>>(h_lig, NL, att_w1 + 128 * 128,
                                             proj_w1 + 128 * 128, att_b1, proj_b1,
                                             LA, LP, 0);

  k_scan<<<1, 1024, 0, stream>>>(counts, offsets, cursor, NL);
  k_scatter<<<4096, 256, 0, stream>>>(p_idx, l_idx, NE, cursor, sorted_p);

  k_edge<<<(NL + 3) / 4, 256, 0, stream>>>(PAPP, Gq, LA, LP, prot_pos, lig_pos,
                                           offsets, counts, sorted_p,
                                           att_w2, att_b2, proj_w2, proj_b2,
                                           h_lig, ln_g, ln_b, out, NP, NL);
}

// Round 6
// 569.253 us; speedup vs baseline: 4.2286x; 4.2286x over previous
//
#include <hip/hip_runtime.h>
#include <cstdint>

// ---------------------------------------------------------------------------
// CrossGraphMessagePassing:
//   PAPP[p][256] = interleaved {h_prot @ att_w1[0:128], h_prot @ proj_w1[0:128]}
//   LA[l] = h_lig @ att_w1[128:256] + b1a ; LP[l] = h_lig @ proj_w1[128:256] + b1p
//   Gq[20][256]  = geo-weight rows (att/proj interleaved per lane dim-pair)
//   per edge: pre = PAPP[p]+L+geo@Wg ; logit = silu(pre_a)@w2+b2
//             w=exp(logit) (|logit|<<1 -> segment-max not needed), g=exp(-d^2/32)
//             per-ligand: num += w*g*silu(pre_p), den += w, gws += w*g
//   per lig:  agg = (num/den)@proj_w2 + (gws/den)*proj_b2 ; out = LN(h_lig+agg)
// Edges counting-sorted by ligand. k_edge: ONE WAVE PER LIGAND, Phase A
// (lane==edge: scalar geo -> LDS), Phase B (wave-wide over dims, 2 edges in
// flight, gathers prefetched 1 iter ahead, consumed at END of FMA chain,
// geo chain in packed-fp32 v_pk_fma).
// NOTE (r5 post-mortem): __launch_bounds__(256,5) forced VGPR 48 -> G[20]
// spilled to scratch -> 7.7 GB HBM traffic, 5x slowdown. Plain (256) gives
// VGPR ~92, no spill. Do NOT re-add a min-waves bound here.
// ---------------------------------------------------------------------------

typedef float f2 __attribute__((ext_vector_type(2)));

__device__ __forceinline__ float fast_rcp(float x) { return __builtin_amdgcn_rcpf(x); }
__device__ __forceinline__ float siluf(float x) { return x * fast_rcp(1.0f + __expf(-x)); }
__device__ __forceinline__ f2 mk2(float a, float b) { f2 r; r.x = a; r.y = b; return r; }
__device__ __forceinline__ f2 fma2(f2 a, f2 b, f2 c) { return __builtin_elementwise_fma(a, b, c); }
__device__ __forceinline__ f2 silu2(f2 x) {
  return mk2(x.x * fast_rcp(1.0f + __expf(-x.x)),
             x.y * fast_rcp(1.0f + __expf(-x.y)));
}

// fused: copy h_prot -> out, build Gq, histogram l_idx
__global__ __launch_bounds__(256) void k_prep(
    const float4* __restrict__ hp4, float4* __restrict__ out4, int n4,
    const float* __restrict__ att_w1, const float* __restrict__ proj_w1,
    float* __restrict__ Gq,
    const int* __restrict__ l_idx, int ne, int* __restrict__ counts) {
  int i = blockIdx.x * blockDim.x + threadIdx.x;
  int stride = gridDim.x * blockDim.x;
  for (int j = i; j < n4; j += stride) out4[j] = hp4[j];
  for (int j = i; j < 20 * 256; j += stride) {
    int k = j >> 8, r = j & 255;
    int ln = r >> 2, c = r & 3;
    int d = 2 * ln + (c & 1);
    const float* src = (c < 2) ? att_w1 : proj_w1;
    Gq[j] = src[(256 + k) * 128 + d];
  }
  for (int j = i; j < ne; j += stride) atomicAdd(&counts[l_idx[j]], 1);
}

// Tables: 8 rows/block, 256 threads (t<128 -> att col d, t>=128 -> proj col d).
// interleaved==1: write into one [row][256] table as {A0,A1,P0,P1} per dim-pair.
__global__ __launch_bounds__(256) void k_tables(
    const float* __restrict__ h, int nrows,
    const float* __restrict__ Wa, const float* __restrict__ Wp,   // 128x128 (k,d)
    const float* __restrict__ ba, const float* __restrict__ bp,   // nullable
    float* __restrict__ TA, float* __restrict__ TP, int interleaved) {
  __shared__ float hT[128 * 8];  // [k][r]
  int t = threadIdx.x;
  int row0 = blockIdx.x * 8;
  for (int i = t; i < 1024; i += 256) {
    int r = i >> 7, k = i & 127;
    int gr = row0 + r;
    hT[k * 8 + r] = (gr < nrows) ? h[gr * 128 + k] : 0.0f;
  }
  __syncthreads();
  const float* W = (t < 128) ? Wa : Wp;
  const float* bias = (t < 128) ? ba : bp;
  int d = t & 127;
  float acc[8] = {0, 0, 0, 0, 0, 0, 0, 0};
  for (int k = 0; k < 128; ++k) {
    float w = W[k * 128 + d];
    const float4* h4 = reinterpret_cast<const float4*>(&hT[k * 8]);
    float4 a = h4[0], b = h4[1];
    acc[0] += a.x * w; acc[1] += a.y * w; acc[2] += a.z * w; acc[3] += a.w * w;
    acc[4] += b.x * w; acc[5] += b.y * w; acc[6] += b.z * w; acc[7] += b.w * w;
  }
  float bv = bias ? bias[d] : 0.0f;
  if (interleaved) {
    int pos = ((d >> 1) << 2) + (d & 1) + ((t < 128) ? 0 : 2);
    #pragma unroll
    for (int r = 0; r < 8; ++r) {
      int gr = row0 + r;
      if (gr < nrows) TA[(size_t)gr * 256 + pos] = acc[r] + bv;
    }
  } else {
    float* T = (t < 128) ? TA : TP;
    #pragma unroll
    for (int r = 0; r < 8; ++r) {
      int gr = row0 + r;
      if (gr < nrows) T[(size_t)gr * 128 + d] = acc[r] + bv;
    }
  }
}

__global__ __launch_bounds__(1024) void k_scan(const int* __restrict__ counts,
                                               int* __restrict__ offsets,
                                               int* __restrict__ cursor, int n) {
  __shared__ int tsum[1024];
  int t = threadIdx.x;
  int per = (n + 1023) >> 10;
  int base = t * per;
  int s = 0;
  for (int i = 0; i < per; ++i) {
    int idx = base + i;
    if (idx < n) s += counts[idx];
  }
  tsum[t] = s;
  __syncthreads();
  for (int off = 1; off < 1024; off <<= 1) {
    int v = (t >= off) ? tsum[t - off] : 0;
    __syncthreads();
    tsum[t] += v;
    __syncthreads();
  }
  int run = (t == 0) ? 0 : tsum[t - 1];
  for (int i = 0; i < per; ++i) {
    int idx = base + i;
    if (idx < n) {
      offsets[idx] = run;
      cursor[idx] = run;
      run += counts[idx];
    }
  }
}

__global__ void k_scatter(const int* __restrict__ p_idx, const int* __restrict__ l_idx, int ne,
                          int* __restrict__ cursor, int* __restrict__ sorted_p) {
  int i = blockIdx.x * blockDim.x + threadIdx.x;
  int stride = gridDim.x * blockDim.x;
  for (; i < ne; i += stride) {
    int l = l_idx[i];
    int pos = atomicAdd(&cursor[l], 1);
    sorted_p[pos] = p_idx[i];
  }
}

// ONE WAVE PER LIGAND. 256 threads = 4 waves = 4 ligands/block. No barriers.
__global__ __launch_bounds__(256) void k_edge(
    const float* __restrict__ PAPP, const float* __restrict__ Gq,
    const float* __restrict__ LA, const float* __restrict__ LP,
    const float* __restrict__ prot_pos, const float* __restrict__ lig_pos,
    const int* __restrict__ offsets, const int* __restrict__ counts,
    const int* __restrict__ sorted_p,
    const float* __restrict__ att_w2, const float* __restrict__ att_b2,
    const float* __restrict__ proj_w2, const float* __restrict__ proj_b2,
    const float* __restrict__ h_lig, const float* __restrict__ ln_g,
    const float* __restrict__ ln_b,
    float* __restrict__ out, int np_total, int nl_total) {
  __shared__ alignas(16) float geoS[4][64][24];  // [wave][edge][field]
  __shared__ alignas(16) int pS[4][64];

  int t = threadIdx.x;
  int wave = t >> 6, lane = t & 63;
  int l = blockIdx.x * 4 + wave;
  if (l >= nl_total) return;  // whole-wave exit; no barriers in kernel
  int dd = 2 * lane;

  // per-lane geo weights: 20 x float4 {Ga(dd), Ga(dd+1), Gp(dd), Gp(dd+1)}
  const float4* Gq4 = reinterpret_cast<const float4*>(Gq);
  float4 G[20];
  #pragma unroll
  for (int k = 0; k < 20; ++k) G[k] = Gq4[k * 64 + lane];

  float2 lav = *reinterpret_cast<const float2*>(&LA[(size_t)l * 128 + dd]);
  float2 lpv = *reinterpret_cast<const float2*>(&LP[(size_t)l * 128 + dd]);
  float2 wav = *reinterpret_cast<const float2*>(&att_w2[dd]);
  f2 lA2 = mk2(lav.x, lav.y);
  f2 lP2 = mk2(lpv.x, lpv.y);
  float wa0 = wav.x, wa1 = wav.y;
  float lx = lig_pos[l * 3 + 0], ly = lig_pos[l * 3 + 1], lz = lig_pos[l * 3 + 2];
  float b2 = att_b2[0];

  int start = offsets[l];
  int cnt = counts[l];
  f2 acc2 = mk2(0.0f, 0.0f);
  float den = 0.0f, gws = 0.0f;

  const float4* PAPP4 = reinterpret_cast<const float4*>(PAPP);

  for (int cbase = 0; cbase < cnt; cbase += 64) {
    int cc = min(64, cnt - cbase);
    // ---- Phase A: one edge per lane (scalar geo, native exps -> LDS) ----
    if (lane < cc) {
      int p = sorted_p[start + cbase + lane];
      float px = prot_pos[p * 3 + 0], py = prot_pos[p * 3 + 1], pz = prot_pos[p * 3 + 2];
      float dx = lx - px, dy = ly - py, dz = lz - pz;
      float d2r = dx * dx + dy * dy + dz * dz;
      float dist = sqrtf(d2r);
      float inv = fast_rcp(dist + 1e-8f);
      float rb[16];
      #pragma unroll
      for (int j = 0; j < 16; ++j) {
        float c = (8.0f / 15.0f) * (float)j;  // linspace(0, 8, 16)
        float dv = dist - c;
        rb[j] = __expf(-2.0f * dv * dv);      // gamma = 2
      }
      float4* dst = reinterpret_cast<float4*>(&geoS[wave][lane][0]);
      dst[0] = make_float4(dist, dx * inv, dy * inv, dz * inv);
      dst[1] = make_float4(rb[0], rb[1], rb[2], rb[3]);
      dst[2] = make_float4(rb[4], rb[5], rb[6], rb[7]);
      dst[3] = make_float4(rb[8], rb[9], rb[10], rb[11]);
      dst[4] = make_float4(rb[12], rb[13], rb[14], rb[15]);
      geoS[wave][lane][20] = __expf(-d2r * (1.0f / 32.0f));
      pS[wave][lane] = p;
    }
    // ---- Phase B: wave-wide, 2 edges in flight, 1-iter gather prefetch ----
    int pA0 = __builtin_amdgcn_readfirstlane(pS[wave][0]);
    int pB0 = __builtin_amdgcn_readfirstlane(pS[wave][cc > 1 ? 1 : 0]);
    float4 tvA = PAPP4[(size_t)pA0 * 64 + lane];
    float4 tvB = PAPP4[(size_t)pB0 * 64 + lane];
    for (int e = 0; e < cc; e += 2) {
      int eB = (e + 1 < cc) ? e + 1 : e;
      float maskB = (e + 1 < cc) ? 1.0f : 0.0f;
      int e2 = e + 2;
      int iA2 = (e2 < cc) ? e2 : 0;
      int iB2 = (e2 + 1 < cc) ? e2 + 1 : 0;
      int pA2 = __builtin_amdgcn_readfirstlane(pS[wave][iA2]);
      int pB2 = __builtin_amdgcn_readfirstlane(pS[wave][iB2]);
      float4 ntA = PAPP4[(size_t)pA2 * 64 + lane];   // prefetch: consumed next iter
      float4 ntB = PAPP4[(size_t)pB2 * 64 + lane];

      const float4* gA4 = reinterpret_cast<const float4*>(&geoS[wave][e][0]);
      const float4* gB4 = reinterpret_cast<const float4*>(&geoS[wave][eB][0]);
      f2 aA = lA2, vA = lP2, aB = lA2, vB = lP2;
      #pragma unroll
      for (int k4 = 0; k4 < 5; ++k4) {
        float4 qA = gA4[k4];
        float4 qB = gB4[k4];
        int k = 4 * k4;
        f2 ga, gp;
        ga = mk2(G[k].x, G[k].y);         gp = mk2(G[k].z, G[k].w);
        aA = fma2(mk2(qA.x, qA.x), ga, aA); vA = fma2(mk2(qA.x, qA.x), gp, vA);
        aB = fma2(mk2(qB.x, qB.x), ga, aB); vB = fma2(mk2(qB.x, qB.x), gp, vB);
        ga = mk2(G[k + 1].x, G[k + 1].y); gp = mk2(G[k + 1].z, G[k + 1].w);
        aA = fma2(mk2(qA.y, qA.y), ga, aA); vA = fma2(mk2(qA.y, qA.y), gp, vA);
        aB = fma2(mk2(qB.y, qB.y), ga, aB); vB = fma2(mk2(qB.y, qB.y), gp, vB);
        ga = mk2(G[k + 2].x, G[k + 2].y); gp = mk2(G[k + 2].z, G[k + 2].w);
        aA = fma2(mk2(qA.z, qA.z), ga, aA); vA = fma2(mk2(qA.z, qA.z), gp, vA);
        aB = fma2(mk2(qB.z, qB.z), ga, aB); vB = fma2(mk2(qB.z, qB.z), gp, vB);
        ga = mk2(G[k + 3].x, G[k + 3].y); gp = mk2(G[k + 3].z, G[k + 3].w);
        aA = fma2(mk2(qA.w, qA.w), ga, aA); vA = fma2(mk2(qA.w, qA.w), gp, vA);
        aB = fma2(mk2(qB.w, qB.w), ga, aB); vB = fma2(mk2(qB.w, qB.w), gp, vB);
      }
      // gathered table rows join at the END of the chain (latency hiding)
      aA = aA + mk2(tvA.x, tvA.y); vA = vA + mk2(tvA.z, tvA.w);
      aB = aB + mk2(tvB.x, tvB.y); vB = vB + mk2(tvB.z, tvB.w);

      f2 hA = silu2(aA), hB = silu2(aB);
      float partA = hA.x * wa0 + hA.y * wa1;
      float partB = hB.x * wa0 + hB.y * wa1;
      #pragma unroll
      for (int off = 32; off; off >>= 1) {
        partA += __shfl_xor(partA, off);
        partB += __shfl_xor(partB, off);
      }
      float gAv = geoS[wave][e][20];
      float gBv = geoS[wave][eB][20];
      float wAe = __expf(partA + b2);
      float wBe = __expf(partB + b2) * maskB;
      float wgA = wAe * gAv, wgB = wBe * gBv;
      f2 sA = silu2(vA), sB = silu2(vB);
      acc2 = fma2(mk2(wgA, wgA), sA, acc2);
      acc2 = fma2(mk2(wgB, wgB), sB, acc2);
      den += wAe + wBe;
      gws += wgA + wgB;
      tvA = ntA; tvB = ntB;
    }
  }

  // ---- per-wave epilogue (no barriers); reuse geoS as accumulator buffer ----
  float invd = 1.0f / (den + 1e-9f);
  float* accW = &geoS[wave][0][0];  // first 128 floats of this wave's region
  *reinterpret_cast<float2*>(&accW[dd]) = make_float2(acc2.x * invd, acc2.y * invd);
  const float2* W2_2 = reinterpret_cast<const float2*>(proj_w2);
  float agg0 = 0.0f, agg1 = 0.0f;
  #pragma unroll 4
  for (int k = 0; k < 128; k += 4) {
    float4 av = *reinterpret_cast<const float4*>(&accW[k]);
    float2 w0 = W2_2[(size_t)(k + 0) * 64 + lane];
    float2 w1 = W2_2[(size_t)(k + 1) * 64 + lane];
    float2 w2 = W2_2[(size_t)(k + 2) * 64 + lane];
    float2 w3 = W2_2[(size_t)(k + 3) * 64 + lane];
    agg0 += av.x * w0.x + av.y * w1.x + av.z * w2.x + av.w * w3.x;
    agg1 += av.x * w0.y + av.y * w1.y + av.z * w2.y + av.w * w3.y;
  }
  float gval = gws * invd;
  float2 pb2 = *reinterpret_cast<const float2*>(&proj_b2[dd]);
  float2 hl = *reinterpret_cast<const float2*>(&h_lig[(size_t)l * 128 + dd]);
  float x0 = agg0 + gval * pb2.x + hl.x;
  float x1 = agg1 + gval * pb2.y + hl.y;
  float s = x0 + x1, q = x0 * x0 + x1 * x1;
  #pragma unroll
  for (int off = 32; off; off >>= 1) {
    s += __shfl_xor(s, off);
    q += __shfl_xor(q, off);
  }
  float mu = s * (1.0f / 128.0f);
  float var = q * (1.0f / 128.0f) - mu * mu;
  float rstd = rsqrtf(var + 1e-5f);
  float2 gm = *reinterpret_cast<const float2*>(&ln_g[dd]);
  float2 bt = *reinterpret_cast<const float2*>(&ln_b[dd]);
  float2 y = make_float2((x0 - mu) * rstd * gm.x + bt.x,
                         (x1 - mu) * rstd * gm.y + bt.y);
  *reinterpret_cast<float2*>(&out[(size_t)(np_total + l) * 128 + dd]) = y;
}

extern "C" void kernel_launch(void* const* d_in, const int* in_sizes, int n_in,
                              void* d_out, int out_size, void* d_ws, size_t ws_size,
                              hipStream_t stream) {
  const float* h_prot   = (const float*)d_in[0];
  const float* h_lig    = (const float*)d_in[1];
  const float* prot_pos = (const float*)d_in[2];
  const float* lig_pos  = (const float*)d_in[3];
  const int*   edges    = (const int*)d_in[4];
  const float* att_w1   = (const float*)d_in[5];
  const float* att_b1   = (const float*)d_in[6];
  const float* att_w2   = (const float*)d_in[7];
  const float* att_b2   = (const float*)d_in[8];
  const float* proj_w1  = (const float*)d_in[9];
  const float* proj_b1  = (const float*)d_in[10];
  const float* proj_w2  = (const float*)d_in[11];
  const float* proj_b2  = (const float*)d_in[12];
  const float* ln_g     = (const float*)d_in[13];
  const float* ln_b     = (const float*)d_in[14];

  int NP = in_sizes[0] / 128;
  int NL = in_sizes[1] / 128;
  int NE = in_sizes[4] / 2;
  const int* p_idx = edges;
  const int* l_idx = edges + NE;

  float* out = (float*)d_out;

  // workspace layout
  float* PAPP = (float*)d_ws;                      // NP x 256, interleaved A/P
  float* LA = PAPP + (size_t)NP * 256;
  float* LP = LA + (size_t)NL * 128;
  float* Gq = LP + (size_t)NL * 128;               // 20 x 256
  int* counts  = (int*)(Gq + 20 * 256);
  int* offsets = counts + NL;
  int* cursor  = offsets + NL;
  int* sorted_p = cursor + NL;

  hipMemsetAsync(counts, 0, (size_t)NL * sizeof(int), stream);

  k_prep<<<2048, 256, 0, stream>>>((const float4*)h_prot, (float4*)out, NP * 128 / 4,
                                   att_w1, proj_w1, Gq, l_idx, NE, counts);

  k_tables<<<(NP + 7) / 8, 256, 0, stream>>>(h_prot, NP, att_w1, proj_w1,
                                             nullptr, nullptr, PAPP, nullptr, 1);
  k_tables<<<(NL + 7) / 8, 256, 0, stream>>>(h_lig, NL, att_w1 + 128 * 128,
                                             proj_w1 + 128 * 128, att_b1, proj_b1,
                                             LA, LP, 0);

  k_scan<<<1, 1024, 0, stream>>>(counts, offsets, cursor, NL);
  k_scatter<<<4096, 256, 0, stream>>>(p_idx, l_idx, NE, cursor, sorted_p);

  k_edge<<<(NL + 3) / 4, 256, 0, stream>>>(PAPP, Gq, LA, LP, prot_pos, lig_pos,
                                           offsets, counts, sorted_p,
                                           att_w2, att_b2, proj_w2, proj_b2,
                                           h_lig, ln_g, ln_b, out, NP, NL);
}

// Round 8
// 554.062 us; speedup vs baseline: 4.3446x; 1.0274x over previous
//
#include <hip/hip_runtime.h>
#include <cstdint>

// ---------------------------------------------------------------------------
// CrossGraphMessagePassing:
//   PAPP[p][256] = interleaved {h_prot @ att_w1[0:128], h_prot @ proj_w1[0:128]}
//   LA[l] = h_lig @ att_w1[128:256] + b1a ; LP[l] = h_lig @ proj_w1[128:256] + b1p
//   Gq2[40][128] = geo-weight rows, k-PAIRED per lane dim: row r=4m+grp holds
//                  (W[2m][d], W[2m+1][d]) at cols (2*lane, 2*lane+1)
//   per edge: pre = PAPP[p]+L+geo@Wg ; logit = silu(pre_a)@w2+b2
//             w=exp(logit) (|logit|<<1 -> segment-max not needed), g=exp(-d^2/32)
//             per-ligand: num += w*g*silu(pre_p), den += w, gws += w*g
//   per lig:  agg = (num/den)@proj_w2 + (gws/den)*proj_b2 ; out = LN(h_lig+agg)
// k_edge: ONE WAVE PER LIGAND, no barriers.
//   Phase A: lane==edge (scalar geo -> LDS [64][20]; g,p stay in lane regs)
//   Phase B: wave-wide, split-accumulator v_pk_fma chains (geo pairs come
//            straight from ds_read_b128 quads -> no v_mov packing), tv gather
//            prefetched 1 edge ahead, logit reduce = 4 DPP adds + 4 readlane
//            (zero LDS ops), p/g fetched via readlane from Phase-A registers.
// NOTE (r5 post-mortem): do NOT add a min-waves __launch_bounds__ clamp:
// forcing VGPR down spills G2[40] -> 7.7 GB scratch traffic, 5x slower.
// NOTE (r7): __builtin_amdgcn_update_dpp ctrl must be a compile-time constant
// -> dpp_add takes CTRL as a template parameter.
// ---------------------------------------------------------------------------

typedef float f2 __attribute__((ext_vector_type(2)));
typedef float f4 __attribute__((ext_vector_type(4)));

__device__ __forceinline__ float fast_rcp(float x) { return __builtin_amdgcn_rcpf(x); }
__device__ __forceinline__ float siluf(float x) { return x * fast_rcp(1.0f + __expf(-x)); }
__device__ __forceinline__ f2 fma2(f2 a, f2 b, f2 c) { return __builtin_elementwise_fma(a, b, c); }

template <int CTRL>
__device__ __forceinline__ float dpp_add(float x) {
  int t = __builtin_amdgcn_update_dpp(0, __builtin_bit_cast(int, x), CTRL, 0xF, 0xF, true);
  return x + __builtin_bit_cast(float, t);
}
__device__ __forceinline__ float rdlane(float x, int lane) {
  return __builtin_bit_cast(float, __builtin_amdgcn_readlane(__builtin_bit_cast(int, x), lane));
}
// full 64-lane sum, result uniform in all lanes (no LDS traffic)
__device__ __forceinline__ float wave_sum(float x) {
  x = dpp_add<0xB1>(x);   // quad_perm(1,0,3,2): pair sums
  x = dpp_add<0x4E>(x);   // quad_perm(2,3,0,1): quad sums
  x = dpp_add<0x141>(x);  // row_half_mirror:    8-sums
  x = dpp_add<0x140>(x);  // row_mirror:         16-sums
  float a = rdlane(x, 0), b = rdlane(x, 16), c = rdlane(x, 32), d = rdlane(x, 48);
  return (a + b) + (c + d);
}

// fused: copy h_prot -> out, build Gq2, histogram l_idx
__global__ __launch_bounds__(256) void k_prep(
    const float4* __restrict__ hp4, float4* __restrict__ out4, int n4,
    const float* __restrict__ att_w1, const float* __restrict__ proj_w1,
    float* __restrict__ Gq,
    const int* __restrict__ l_idx, int ne, int* __restrict__ counts) {
  int i = blockIdx.x * blockDim.x + threadIdx.x;
  int stride = gridDim.x * blockDim.x;
  for (int j = i; j < n4; j += stride) out4[j] = hp4[j];
  // Gq2[r=4m+grp][c=2*lane+half] = W[(256+2m+half)*128 + 2*lane+(grp&1)]
  for (int j = i; j < 40 * 128; j += stride) {
    int r = j >> 7, c = j & 127;
    int m = r >> 2, grp = r & 3;
    int lane = c >> 1, half = c & 1;
    const float* src = (grp < 2) ? att_w1 : proj_w1;
    Gq[j] = src[(256 + 2 * m + half) * 128 + 2 * lane + (grp & 1)];
  }
  for (int j = i; j < ne; j += stride) atomicAdd(&counts[l_idx[j]], 1);
}

// Tables: 8 rows/block, 256 threads (t<128 -> att col d, t>=128 -> proj col d).
// interleaved==1: write into one [row][256] table as {A0,A1,P0,P1} per dim-pair.
__global__ __launch_bounds__(256) void k_tables(
    const float* __restrict__ h, int nrows,
    const float* __restrict__ Wa, const float* __restrict__ Wp,   // 128x128 (k,d)
    const float* __restrict__ ba, const float* __restrict__ bp,   // nullable
    float* __restrict__ TA, float* __restrict__ TP, int interleaved) {
  __shared__ float hT[128 * 8];  // [k][r]
  int t = threadIdx.x;
  int row0 = blockIdx.x * 8;
  for (int i = t; i < 1024; i += 256) {
    int r = i >> 7, k = i & 127;
    int gr = row0 + r;
    hT[k * 8 + r] = (gr < nrows) ? h[gr * 128 + k] : 0.0f;
  }
  __syncthreads();
  const float* W = (t < 128) ? Wa : Wp;
  const float* bias = (t < 128) ? ba : bp;
  int d = t & 127;
  float acc[8] = {0, 0, 0, 0, 0, 0, 0, 0};
  for (int k = 0; k < 128; ++k) {
    float w = W[k * 128 + d];
    const float4* h4 = reinterpret_cast<const float4*>(&hT[k * 8]);
    float4 a = h4[0], b = h4[1];
    acc[0] += a.x * w; acc[1] += a.y * w; acc[2] += a.z * w; acc[3] += a.w * w;
    acc[4] += b.x * w; acc[5] += b.y * w; acc[6] += b.z * w; acc[7] += b.w * w;
  }
  float bv = bias ? bias[d] : 0.0f;
  if (interleaved) {
    int pos = ((d >> 1) << 2) + (d & 1) + ((t < 128) ? 0 : 2);
    #pragma unroll
    for (int r = 0; r < 8; ++r) {
      int gr = row0 + r;
      if (gr < nrows) TA[(size_t)gr * 256 + pos] = acc[r] + bv;
    }
  } else {
    float* T = (t < 128) ? TA : TP;
    #pragma unroll
    for (int r = 0; r < 8; ++r) {
      int gr = row0 + r;
      if (gr < nrows) T[(size_t)gr * 128 + d] = acc[r] + bv;
    }
  }
}

__global__ __launch_bounds__(1024) void k_scan(const int* __restrict__ counts,
                                               int* __restrict__ offsets,
                                               int* __restrict__ cursor, int n) {
  __shared__ int tsum[1024];
  int t = threadIdx.x;
  int per = (n + 1023) >> 10;
  int base = t * per;
  int s = 0;
  for (int i = 0; i < per; ++i) {
    int idx = base + i;
    if (idx < n) s += counts[idx];
  }
  tsum[t] = s;
  __syncthreads();
  for (int off = 1; off < 1024; off <<= 1) {
    int v = (t >= off) ? tsum[t - off] : 0;
    __syncthreads();
    tsum[t] += v;
    __syncthreads();
  }
  int run = (t == 0) ? 0 : tsum[t - 1];
  for (int i = 0; i < per; ++i) {
    int idx = base + i;
    if (idx < n) {
      offsets[idx] = run;
      cursor[idx] = run;
      run += counts[idx];
    }
  }
}

__global__ void k_scatter(const int* __restrict__ p_idx, const int* __restrict__ l_idx, int ne,
                          int* __restrict__ cursor, int* __restrict__ sorted_p) {
  int i = blockIdx.x * blockDim.x + threadIdx.x;
  int stride = gridDim.x * blockDim.x;
  for (; i < ne; i += stride) {
    int l = l_idx[i];
    int pos = atomicAdd(&cursor[l], 1);
    sorted_p[pos] = p_idx[i];
  }
}

// ONE WAVE PER LIGAND. 256 threads = 4 waves = 4 ligands/block. No barriers.
__global__ __launch_bounds__(256) void k_edge(
    const float* __restrict__ PAPP, const float* __restrict__ Gq,
    const float* __restrict__ LA, const float* __restrict__ LP,
    const float* __restrict__ prot_pos, const float* __restrict__ lig_pos,
    const int* __restrict__ offsets, const int* __restrict__ counts,
    const int* __restrict__ sorted_p,
    const float* __restrict__ att_w2, const float* __restrict__ att_b2,
    const float* __restrict__ proj_w2, const float* __restrict__ proj_b2,
    const float* __restrict__ h_lig, const float* __restrict__ ln_g,
    const float* __restrict__ ln_b,
    float* __restrict__ out, int np_total, int nl_total) {
  __shared__ alignas(16) float geoS[4][64][20];  // [wave][edge][feature]

  int t = threadIdx.x;
  int wave = t >> 6, lane = t & 63;
  int l = blockIdx.x * 4 + wave;
  if (l >= nl_total) return;  // whole-wave exit; no barriers in kernel
  int dd = 2 * lane;

  // per-lane geo weights as k-pairs: G2[4m+grp] = (W[2m][dim], W[2m+1][dim])
  const f2* Gq2 = reinterpret_cast<const f2*>(Gq);
  f2 G2[40];
  #pragma unroll
  for (int r = 0; r < 40; ++r) G2[r] = Gq2[r * 64 + lane];

  float2 lav = *reinterpret_cast<const float2*>(&LA[(size_t)l * 128 + dd]);
  float2 lpv = *reinterpret_cast<const float2*>(&LP[(size_t)l * 128 + dd]);
  float2 wav = *reinterpret_cast<const float2*>(&att_w2[dd]);
  float la0 = lav.x, la1 = lav.y, lp0 = lpv.x, lp1 = lpv.y;
  float wa0 = wav.x, wa1 = wav.y;
  float lx = lig_pos[l * 3 + 0], ly = lig_pos[l * 3 + 1], lz = lig_pos[l * 3 + 2];
  float b2 = att_b2[0];

  int start = offsets[l];
  int cnt = counts[l];
  float acc0 = 0.0f, acc1 = 0.0f, den = 0.0f, gws = 0.0f;

  const float4* PAPP4 = reinterpret_cast<const float4*>(PAPP);

  for (int cbase = 0; cbase < cnt; cbase += 64) {
    int cc = min(64, cnt - cbase);
    // ---- Phase A: one edge per lane (scalar geo -> LDS; g,p stay in regs) ----
    float gReg = 0.0f;
    int pReg = 0;
    if (lane < cc) {
      int p = sorted_p[start + cbase + lane];
      pReg = p;
      float px = prot_pos[p * 3 + 0], py = prot_pos[p * 3 + 1], pz = prot_pos[p * 3 + 2];
      float dx = lx - px, dy = ly - py, dz = lz - pz;
      float d2r = dx * dx + dy * dy + dz * dz;
      float dist = sqrtf(d2r);
      float inv = fast_rcp(dist + 1e-8f);
      float rb[16];
      #pragma unroll
      for (int j = 0; j < 16; ++j) {
        float c = (8.0f / 15.0f) * (float)j;  // linspace(0, 8, 16)
        float dv = dist - c;
        rb[j] = __expf(-2.0f * dv * dv);      // gamma = 2
      }
      f4* dst = reinterpret_cast<f4*>(&geoS[wave][lane][0]);
      f4 w0; w0[0] = dist; w0[1] = dx * inv; w0[2] = dy * inv; w0[3] = dz * inv;
      f4 w1; w1[0] = rb[0]; w1[1] = rb[1]; w1[2] = rb[2]; w1[3] = rb[3];
      f4 w2; w2[0] = rb[4]; w2[1] = rb[5]; w2[2] = rb[6]; w2[3] = rb[7];
      f4 w3; w3[0] = rb[8]; w3[1] = rb[9]; w3[2] = rb[10]; w3[3] = rb[11];
      f4 w4; w4[0] = rb[12]; w4[1] = rb[13]; w4[2] = rb[14]; w4[3] = rb[15];
      dst[0] = w0; dst[1] = w1; dst[2] = w2; dst[3] = w3; dst[4] = w4;
      gReg = __expf(-d2r * (1.0f / 32.0f));
    }
    // ---- Phase B: wave-wide, one edge at a time, 1-ahead tv prefetch ----
    int p0 = __builtin_amdgcn_readlane(pReg, 0);
    float4 tv = PAPP4[(size_t)p0 * 64 + lane];
    for (int e = 0; e < cc; ++e) {
      int en = (e + 1 < cc) ? e + 1 : e;
      int pn = __builtin_amdgcn_readlane(pReg, en);
      float4 nt = PAPP4[(size_t)pn * 64 + lane];   // prefetch: consumed next iter

      const f4* q4 = reinterpret_cast<const f4*>(&geoS[wave][e][0]);
      f2 cA0 = {0.0f, 0.0f}, cA1 = {0.0f, 0.0f};
      f2 cP0 = {0.0f, 0.0f}, cP1 = {0.0f, 0.0f};
      #pragma unroll
      for (int j = 0; j < 5; ++j) {
        f4 q = q4[j];                               // broadcast ds_read_b128
        f2 qlo = __builtin_shufflevector(q, q, 0, 1);
        f2 qhi = __builtin_shufflevector(q, q, 2, 3);
        cA0 = fma2(qlo, G2[8 * j + 0], cA0);
        cA1 = fma2(qlo, G2[8 * j + 1], cA1);
        cP0 = fma2(qlo, G2[8 * j + 2], cP0);
        cP1 = fma2(qlo, G2[8 * j + 3], cP1);
        cA0 = fma2(qhi, G2[8 * j + 4], cA0);
        cA1 = fma2(qhi, G2[8 * j + 5], cA1);
        cP0 = fma2(qhi, G2[8 * j + 6], cP0);
        cP1 = fma2(qhi, G2[8 * j + 7], cP1);
      }
      float a0 = (cA0.x + cA0.y) + (la0 + tv.x);
      float a1 = (cA1.x + cA1.y) + (la1 + tv.y);
      float pp0 = (cP0.x + cP0.y) + (lp0 + tv.z);
      float pp1 = (cP1.x + cP1.y) + (lp1 + tv.w);

      float part = siluf(a0) * wa0 + siluf(a1) * wa1;
      float tot = wave_sum(part);                   // pure-VALU reduce
      float w = __expf(tot + b2);
      float g = rdlane(gReg, e);
      float wg = w * g;
      acc0 = fmaf(wg, siluf(pp0), acc0);
      acc1 = fmaf(wg, siluf(pp1), acc1);
      den += w;
      gws += wg;
      tv = nt;
    }
  }

  // ---- per-wave epilogue (no barriers); reuse geoS as accumulator buffer ----
  float invd = 1.0f / (den + 1e-9f);
  float* accW = &geoS[wave][0][0];  // first 128 floats of this wave's region
  *reinterpret_cast<float2*>(&accW[dd]) = make_float2(acc0 * invd, acc1 * invd);
  const float2* W2_2 = reinterpret_cast<const float2*>(proj_w2);
  float agg0 = 0.0f, agg1 = 0.0f;
  #pragma unroll 4
  for (int k = 0; k < 128; k += 4) {
    float4 av = *reinterpret_cast<const float4*>(&accW[k]);
    float2 w0 = W2_2[(size_t)(k + 0) * 64 + lane];
    float2 w1 = W2_2[(size_t)(k + 1) * 64 + lane];
    float2 w2 = W2_2[(size_t)(k + 2) * 64 + lane];
    float2 w3 = W2_2[(size_t)(k + 3) * 64 + lane];
    agg0 += av.x * w0.x + av.y * w1.x + av.z * w2.x + av.w * w3.x;
    agg1 += av.x * w0.y + av.y * w1.y + av.z * w2.y + av.w * w3.y;
  }
  float gval = gws * invd;
  float2 pb2 = *reinterpret_cast<const float2*>(&proj_b2[dd]);
  float2 hl = *reinterpret_cast<const float2*>(&h_lig[(size_t)l * 128 + dd]);
  float x0 = agg0 + gval * pb2.x + hl.x;
  float x1 = agg1 + gval * pb2.y + hl.y;
  float s = x0 + x1, q = x0 * x0 + x1 * x1;
  s = wave_sum(s);
  q = wave_sum(q);
  float mu = s * (1.0f / 128.0f);
  float var = q * (1.0f / 128.0f) - mu * mu;
  float rstd = rsqrtf(var + 1e-5f);
  float2 gm = *reinterpret_cast<const float2*>(&ln_g[dd]);
  float2 bt = *reinterpret_cast<const float2*>(&ln_b[dd]);
  float2 y = make_float2((x0 - mu) * rstd * gm.x + bt.x,
                         (x1 - mu) * rstd * gm.y + bt.y);
  *reinterpret_cast<float2*>(&out[(size_t)(np_total + l) * 128 + dd]) = y;
}

extern "C" void kernel_launch(void* const* d_in, const int* in_sizes, int n_in,
                              void* d_out, int out_size, void* d_ws, size_t ws_size,
                              hipStream_t stream) {
  const float* h_prot   = (const float*)d_in[0];
  const float* h_lig    = (const float*)d_in[1];
  const float* prot_pos = (const float*)d_in[2];
  const float* lig_pos  = (const float*)d_in[3];
  const int*   edges    = (const int*)d_in[4];
  const float* att_w1   = (const float*)d_in[5];
  const float* att_b1   = (const float*)d_in[6];
  const float* att_w2   = (const float*)d_in[7];
  const float* att_b2   = (const float*)d_in[8];
  const float* proj_w1  = (const float*)d_in[9];
  const float* proj_b1  = (const float*)d_in[10];
  const float* proj_w2  = (const float*)d_in[11];
  const float* proj_b2  = (const float*)d_in[12];
  const float* ln_g     = (const float*)d_in[13];
  const float* ln_b     = (const float*)d_in[14];

  int NP = in_sizes[0] / 128;
  int NL = in_sizes[1] / 128;
  int NE = in_sizes[4] / 2;
  const int* p_idx = edges;
  const int* l_idx = edges + NE;

  float* out = (float*)d_out;

  // workspace layout
  float* PAPP = (float*)d_ws;                      // NP x 256, interleaved A/P
  float* LA = PAPP + (size_t)NP * 256;
  float* LP = LA + (size_t)NL * 128;
  float* Gq = LP + (size_t)NL * 128;               // 40 x 128 (k-paired layout)
  int* counts  = (int*)(Gq + 40 * 128);
  int* offsets = counts + NL;
  int* cursor  = offsets + NL;
  int* sorted_p = cursor + NL;

  (void)hipMemsetAsync(counts, 0, (size_t)NL * sizeof(int), stream);

  k_prep<<<2048, 256, 0, stream>>>((const float4*)h_prot, (float4*)out, NP * 128 / 4,
                                   att_w1, proj_w1, Gq, l_idx, NE, counts);

  k_tables<<<(NP + 7) / 8, 256, 0, stream>>>(h_prot, NP, att_w1, proj_w1,
                                             nullptr, nullptr, PAPP, nullptr, 1);
  k_tables<<<(NL + 7) / 8, 256, 0, stream>>>(h_lig, NL, att_w1 + 128 * 128,
                                             proj_w1 + 128 * 128, att_b1, proj_b1,
                                             LA, LP, 0);

  k_scan<<<1, 1024, 0, stream>>>(counts, offsets, cursor, NL);
  k_scatter<<<4096, 256, 0, stream>>>(p_idx, l_idx, NE, cursor, sorted_p);

  k_edge<<<(NL + 3) / 4, 256, 0, stream>>>(PAPP, Gq, LA, LP, prot_pos, lig_pos,
                                           offsets, counts, sorted_p,
                                           att_w2, att_b2, proj_w2, proj_b2,
                                           h_lig, ln_g, ln_b, out, NP, NL);
}

// Round 9
// 535.823 us; speedup vs baseline: 4.4925x; 1.0340x over previous
//
#include <hip/hip_runtime.h>
#include <cstdint>

// ---------------------------------------------------------------------------
// CrossGraphMessagePassing:
//   PAPP[p][256] = interleaved {h_prot @ att_w1[0:128], h_prot @ proj_w1[0:128]}
//   LA[l] = h_lig @ att_w1[128:256] + b1a ; LP[l] = h_lig @ proj_w1[128:256] + b1p
//   Gq2[40][128] = geo-weight rows, k-PAIRED per lane dim
//   per edge: pre = PAPP[p]+L+geo@Wg ; logit = silu(pre_a)@w2+b2
//             w=exp(logit) (|logit|<<1 -> segment-max not needed), g=exp(-d^2/32)
//             per-ligand: num += w*g*silu(pre_p), den += w, gws += w*g
//   per lig:  agg = (num/den)@proj_w2 + (gws/den)*proj_b2 ; out = LN(h_lig+agg)
// k_edge: ONE WAVE PER LIGAND, ONE WAVE PER BLOCK (64 thr), grid=NL -> 10000
// blocks (r8 post-mortem: occupancy was grid-limited at 2500 blocks).
//   Phase A: lane==edge (scalar geo -> LDS [64][20]; g,p stay in lane regs)
//   Phase B: wave-wide, TWO edges in flight (interleaved FMA chains + DPP
//            reduces), tv gathers prefetched one pair ahead, logit reduce =
//            4 DPP adds + 4 readlane (zero LDS ops).
// NOTE (r5 post-mortem): do NOT add a min-waves __launch_bounds__ clamp:
// forcing VGPR down spills G2[40] -> 7.7 GB scratch traffic, 5x slower.
// NOTE (r7): __builtin_amdgcn_update_dpp ctrl must be a compile-time constant.
// ---------------------------------------------------------------------------

typedef float f2 __attribute__((ext_vector_type(2)));
typedef float f4 __attribute__((ext_vector_type(4)));

__device__ __forceinline__ float fast_rcp(float x) { return __builtin_amdgcn_rcpf(x); }
__device__ __forceinline__ float siluf(float x) { return x * fast_rcp(1.0f + __expf(-x)); }
__device__ __forceinline__ f2 fma2(f2 a, f2 b, f2 c) { return __builtin_elementwise_fma(a, b, c); }

template <int CTRL>
__device__ __forceinline__ float dpp_add(float x) {
  int t = __builtin_amdgcn_update_dpp(0, __builtin_bit_cast(int, x), CTRL, 0xF, 0xF, true);
  return x + __builtin_bit_cast(float, t);
}
__device__ __forceinline__ float rdlane(float x, int lane) {
  return __builtin_bit_cast(float, __builtin_amdgcn_readlane(__builtin_bit_cast(int, x), lane));
}
// full 64-lane sum, result uniform (no LDS traffic)
__device__ __forceinline__ float wave_sum(float x) {
  x = dpp_add<0xB1>(x);
  x = dpp_add<0x4E>(x);
  x = dpp_add<0x141>(x);
  x = dpp_add<0x140>(x);
  float a = rdlane(x, 0), b = rdlane(x, 16), c = rdlane(x, 32), d = rdlane(x, 48);
  return (a + b) + (c + d);
}
// two independent 64-lane sums, chains interleaved for ILP
__device__ __forceinline__ void wave_sum2(float& x, float& y) {
  x = dpp_add<0xB1>(x);  y = dpp_add<0xB1>(y);
  x = dpp_add<0x4E>(x);  y = dpp_add<0x4E>(y);
  x = dpp_add<0x141>(x); y = dpp_add<0x141>(y);
  x = dpp_add<0x140>(x); y = dpp_add<0x140>(y);
  float a0 = rdlane(x, 0), a1 = rdlane(x, 16), a2 = rdlane(x, 32), a3 = rdlane(x, 48);
  float b0 = rdlane(y, 0), b1 = rdlane(y, 16), b2 = rdlane(y, 32), b3 = rdlane(y, 48);
  x = (a0 + a1) + (a2 + a3);
  y = (b0 + b1) + (b2 + b3);
}

// fused: copy h_prot -> out, build Gq2, histogram l_idx
__global__ __launch_bounds__(256) void k_prep(
    const float4* __restrict__ hp4, float4* __restrict__ out4, int n4,
    const float* __restrict__ att_w1, const float* __restrict__ proj_w1,
    float* __restrict__ Gq,
    const int* __restrict__ l_idx, int ne, int* __restrict__ counts) {
  int i = blockIdx.x * blockDim.x + threadIdx.x;
  int stride = gridDim.x * blockDim.x;
  for (int j = i; j < n4; j += stride) out4[j] = hp4[j];
  // Gq2[r=4m+grp][c=2*lane+half] = W[(256+2m+half)*128 + 2*lane+(grp&1)]
  for (int j = i; j < 40 * 128; j += stride) {
    int r = j >> 7, c = j & 127;
    int m = r >> 2, grp = r & 3;
    int lane = c >> 1, half = c & 1;
    const float* src = (grp < 2) ? att_w1 : proj_w1;
    Gq[j] = src[(256 + 2 * m + half) * 128 + 2 * lane + (grp & 1)];
  }
  for (int j = i; j < ne; j += stride) atomicAdd(&counts[l_idx[j]], 1);
}

// Tables: 8 rows/block, 256 threads (t<128 -> att col d, t>=128 -> proj col d).
__global__ __launch_bounds__(256) void k_tables(
    const float* __restrict__ h, int nrows,
    const float* __restrict__ Wa, const float* __restrict__ Wp,   // 128x128 (k,d)
    const float* __restrict__ ba, const float* __restrict__ bp,   // nullable
    float* __restrict__ TA, float* __restrict__ TP, int interleaved) {
  __shared__ float hT[128 * 8];  // [k][r]
  int t = threadIdx.x;
  int row0 = blockIdx.x * 8;
  for (int i = t; i < 1024; i += 256) {
    int r = i >> 7, k = i & 127;
    int gr = row0 + r;
    hT[k * 8 + r] = (gr < nrows) ? h[gr * 128 + k] : 0.0f;
  }
  __syncthreads();
  const float* W = (t < 128) ? Wa : Wp;
  const float* bias = (t < 128) ? ba : bp;
  int d = t & 127;
  float acc[8] = {0, 0, 0, 0, 0, 0, 0, 0};
  for (int k = 0; k < 128; ++k) {
    float w = W[k * 128 + d];
    const float4* h4 = reinterpret_cast<const float4*>(&hT[k * 8]);
    float4 a = h4[0], b = h4[1];
    acc[0] += a.x * w; acc[1] += a.y * w; acc[2] += a.z * w; acc[3] += a.w * w;
    acc[4] += b.x * w; acc[5] += b.y * w; acc[6] += b.z * w; acc[7] += b.w * w;
  }
  float bv = bias ? bias[d] : 0.0f;
  if (interleaved) {
    int pos = ((d >> 1) << 2) + (d & 1) + ((t < 128) ? 0 : 2);
    #pragma unroll
    for (int r = 0; r < 8; ++r) {
      int gr = row0 + r;
      if (gr < nrows) TA[(size_t)gr * 256 + pos] = acc[r] + bv;
    }
  } else {
    float* T = (t < 128) ? TA : TP;
    #pragma unroll
    for (int r = 0; r < 8; ++r) {
      int gr = row0 + r;
      if (gr < nrows) T[(size_t)gr * 128 + d] = acc[r] + bv;
    }
  }
}

__global__ __launch_bounds__(1024) void k_scan(const int* __restrict__ counts,
                                               int* __restrict__ offsets,
                                               int* __restrict__ cursor, int n) {
  __shared__ int tsum[1024];
  int t = threadIdx.x;
  int per = (n + 1023) >> 10;
  int base = t * per;
  int s = 0;
  for (int i = 0; i < per; ++i) {
    int idx = base + i;
    if (idx < n) s += counts[idx];
  }
  tsum[t] = s;
  __syncthreads();
  for (int off = 1; off < 1024; off <<= 1) {
    int v = (t >= off) ? tsum[t - off] : 0;
    __syncthreads();
    tsum[t] += v;
    __syncthreads();
  }
  int run = (t == 0) ? 0 : tsum[t - 1];
  for (int i = 0; i < per; ++i) {
    int idx = base + i;
    if (idx < n) {
      offsets[idx] = run;
      cursor[idx] = run;
      run += counts[idx];
    }
  }
}

__global__ void k_scatter(const int* __restrict__ p_idx, const int* __restrict__ l_idx, int ne,
                          int* __restrict__ cursor, int* __restrict__ sorted_p) {
  int i = blockIdx.x * blockDim.x + threadIdx.x;
  int stride = gridDim.x * blockDim.x;
  for (; i < ne; i += stride) {
    int l = l_idx[i];
    int pos = atomicAdd(&cursor[l], 1);
    sorted_p[pos] = p_idx[i];
  }
}

// ONE WAVE PER LIGAND, ONE WAVE PER BLOCK. grid = NL. No barriers.
__global__ __launch_bounds__(64) void k_edge(
    const float* __restrict__ PAPP, const float* __restrict__ Gq,
    const float* __restrict__ LA, const float* __restrict__ LP,
    const float* __restrict__ prot_pos, const float* __restrict__ lig_pos,
    const int* __restrict__ offsets, const int* __restrict__ counts,
    const int* __restrict__ sorted_p,
    const float* __restrict__ att_w2, const float* __restrict__ att_b2,
    const float* __restrict__ proj_w2, const float* __restrict__ proj_b2,
    const float* __restrict__ h_lig, const float* __restrict__ ln_g,
    const float* __restrict__ ln_b,
    float* __restrict__ out, int np_total, int nl_total) {
  __shared__ alignas(16) float geoS[64][20];  // [edge][feature]

  int lane = threadIdx.x;
  int l = blockIdx.x;
  if (l >= nl_total) return;
  int dd = 2 * lane;

  // per-lane geo weights as k-pairs: G2[4m+grp] = (W[2m][dim], W[2m+1][dim])
  const f2* Gq2 = reinterpret_cast<const f2*>(Gq);
  f2 G2[40];
  #pragma unroll
  for (int r = 0; r < 40; ++r) G2[r] = Gq2[r * 64 + lane];

  float2 lav = *reinterpret_cast<const float2*>(&LA[(size_t)l * 128 + dd]);
  float2 lpv = *reinterpret_cast<const float2*>(&LP[(size_t)l * 128 + dd]);
  float2 wav = *reinterpret_cast<const float2*>(&att_w2[dd]);
  float la0 = lav.x, la1 = lav.y, lp0 = lpv.x, lp1 = lpv.y;
  float wa0 = wav.x, wa1 = wav.y;
  float lx = lig_pos[l * 3 + 0], ly = lig_pos[l * 3 + 1], lz = lig_pos[l * 3 + 2];
  float b2 = att_b2[0];

  int start = offsets[l];
  int cnt = counts[l];
  float acc0 = 0.0f, acc1 = 0.0f, den = 0.0f, gws = 0.0f;

  const float4* PAPP4 = reinterpret_cast<const float4*>(PAPP);

  for (int cbase = 0; cbase < cnt; cbase += 64) {
    int cc = min(64, cnt - cbase);
    // ---- Phase A: one edge per lane (scalar geo -> LDS; g,p stay in regs) ----
    float gReg = 0.0f;
    int pReg = 0;
    if (lane < cc) {
      int p = sorted_p[start + cbase + lane];
      pReg = p;
      float px = prot_pos[p * 3 + 0], py = prot_pos[p * 3 + 1], pz = prot_pos[p * 3 + 2];
      float dx = lx - px, dy = ly - py, dz = lz - pz;
      float d2r = dx * dx + dy * dy + dz * dz;
      float dist = sqrtf(d2r);
      float inv = fast_rcp(dist + 1e-8f);
      float rb[16];
      #pragma unroll
      for (int j = 0; j < 16; ++j) {
        float c = (8.0f / 15.0f) * (float)j;  // linspace(0, 8, 16)
        float dv = dist - c;
        rb[j] = __expf(-2.0f * dv * dv);      // gamma = 2
      }
      f4* dst = reinterpret_cast<f4*>(&geoS[lane][0]);
      f4 w0; w0[0] = dist; w0[1] = dx * inv; w0[2] = dy * inv; w0[3] = dz * inv;
      f4 w1; w1[0] = rb[0]; w1[1] = rb[1]; w1[2] = rb[2]; w1[3] = rb[3];
      f4 w2; w2[0] = rb[4]; w2[1] = rb[5]; w2[2] = rb[6]; w2[3] = rb[7];
      f4 w3; w3[0] = rb[8]; w3[1] = rb[9]; w3[2] = rb[10]; w3[3] = rb[11];
      f4 w4; w4[0] = rb[12]; w4[1] = rb[13]; w4[2] = rb[14]; w4[3] = rb[15];
      dst[0] = w0; dst[1] = w1; dst[2] = w2; dst[3] = w3; dst[4] = w4;
      gReg = __expf(-d2r * (1.0f / 32.0f));
    }
    // ---- Phase B: wave-wide, 2 edges in flight, 1-pair-ahead tv prefetch ----
    int pA0 = __builtin_amdgcn_readlane(pReg, 0);
    int pB0 = __builtin_amdgcn_readlane(pReg, cc > 1 ? 1 : 0);
    float4 tvA = PAPP4[(size_t)pA0 * 64 + lane];
    float4 tvB = PAPP4[(size_t)pB0 * 64 + lane];
    for (int e = 0; e < cc; e += 2) {
      int eB = (e + 1 < cc) ? e + 1 : e;
      float maskB = (e + 1 < cc) ? 1.0f : 0.0f;
      int iA2 = (e + 2 < cc) ? e + 2 : 0;
      int iB2 = (e + 3 < cc) ? e + 3 : 0;
      int pA2 = __builtin_amdgcn_readlane(pReg, iA2);
      int pB2 = __builtin_amdgcn_readlane(pReg, iB2);
      float4 ntA = PAPP4[(size_t)pA2 * 64 + lane];   // consumed next iter
      float4 ntB = PAPP4[(size_t)pB2 * 64 + lane];

      const f4* qA4 = reinterpret_cast<const f4*>(&geoS[e][0]);
      const f4* qB4 = reinterpret_cast<const f4*>(&geoS[eB][0]);
      f2 cAA0 = {0.0f, 0.0f}, cAA1 = {0.0f, 0.0f};
      f2 cAP0 = {0.0f, 0.0f}, cAP1 = {0.0f, 0.0f};
      f2 cBA0 = {0.0f, 0.0f}, cBA1 = {0.0f, 0.0f};
      f2 cBP0 = {0.0f, 0.0f}, cBP1 = {0.0f, 0.0f};
      #pragma unroll
      for (int j = 0; j < 5; ++j) {
        f4 qA = qA4[j];                              // broadcast ds_read_b128
        f4 qB = qB4[j];
        f2 qAlo = __builtin_shufflevector(qA, qA, 0, 1);
        f2 qAhi = __builtin_shufflevector(qA, qA, 2, 3);
        f2 qBlo = __builtin_shufflevector(qB, qB, 0, 1);
        f2 qBhi = __builtin_shufflevector(qB, qB, 2, 3);
        cAA0 = fma2(qAlo, G2[8 * j + 0], cAA0);
        cAA1 = fma2(qAlo, G2[8 * j + 1], cAA1);
        cAP0 = fma2(qAlo, G2[8 * j + 2], cAP0);
        cAP1 = fma2(qAlo, G2[8 * j + 3], cAP1);
        cBA0 = fma2(qBlo, G2[8 * j + 0], cBA0);
        cBA1 = fma2(qBlo, G2[8 * j + 1], cBA1);
        cBP0 = fma2(qBlo, G2[8 * j + 2], cBP0);
        cBP1 = fma2(qBlo, G2[8 * j + 3], cBP1);
        cAA0 = fma2(qAhi, G2[8 * j + 4], cAA0);
        cAA1 = fma2(qAhi, G2[8 * j + 5], cAA1);
        cAP0 = fma2(qAhi, G2[8 * j + 6], cAP0);
        cAP1 = fma2(qAhi, G2[8 * j + 7], cAP1);
        cBA0 = fma2(qBhi, G2[8 * j + 4], cBA0);
        cBA1 = fma2(qBhi, G2[8 * j + 5], cBA1);
        cBP0 = fma2(qBhi, G2[8 * j + 6], cBP0);
        cBP1 = fma2(qBhi, G2[8 * j + 7], cBP1);
      }
      float aA0 = (cAA0.x + cAA0.y) + (la0 + tvA.x);
      float aA1 = (cAA1.x + cAA1.y) + (la1 + tvA.y);
      float pA0v = (cAP0.x + cAP0.y) + (lp0 + tvA.z);
      float pA1v = (cAP1.x + cAP1.y) + (lp1 + tvA.w);
      float aB0 = (cBA0.x + cBA0.y) + (la0 + tvB.x);
      float aB1 = (cBA1.x + cBA1.y) + (la1 + tvB.y);
      float pB0v = (cBP0.x + cBP0.y) + (lp0 + tvB.z);
      float pB1v = (cBP1.x + cBP1.y) + (lp1 + tvB.w);

      float partA = siluf(aA0) * wa0 + siluf(aA1) * wa1;
      float partB = siluf(aB0) * wa0 + siluf(aB1) * wa1;
      wave_sum2(partA, partB);                       // interleaved DPP chains
      float wA = __expf(partA + b2);
      float wB = __expf(partB + b2) * maskB;
      float gA = rdlane(gReg, e);
      float gB = rdlane(gReg, eB);
      float wgA = wA * gA, wgB = wB * gB;
      acc0 = fmaf(wgA, siluf(pA0v), acc0);
      acc1 = fmaf(wgA, siluf(pA1v), acc1);
      acc0 = fmaf(wgB, siluf(pB0v), acc0);
      acc1 = fmaf(wgB, siluf(pB1v), acc1);
      den += wA + wB;
      gws += wgA + wgB;
      tvA = ntA; tvB = ntB;
    }
  }

  // ---- epilogue (single wave); reuse geoS as accumulator buffer ----
  float invd = 1.0f / (den + 1e-9f);
  float* accW = &geoS[0][0];
  *reinterpret_cast<float2*>(&accW[dd]) = make_float2(acc0 * invd, acc1 * invd);
  const float2* W2_2 = reinterpret_cast<const float2*>(proj_w2);
  float agg0 = 0.0f, agg1 = 0.0f;
  #pragma unroll 4
  for (int k = 0; k < 128; k += 4) {
    float4 av = *reinterpret_cast<const float4*>(&accW[k]);
    float2 w0 = W2_2[(size_t)(k + 0) * 64 + lane];
    float2 w1 = W2_2[(size_t)(k + 1) * 64 + lane];
    float2 w2 = W2_2[(size_t)(k + 2) * 64 + lane];
    float2 w3 = W2_2[(size_t)(k + 3) * 64 + lane];
    agg0 += av.x * w0.x + av.y * w1.x + av.z * w2.x + av.w * w3.x;
    agg1 += av.x * w0.y + av.y * w1.y + av.z * w2.y + av.w * w3.y;
  }
  float gval = gws * invd;
  float2 pb2 = *reinterpret_cast<const float2*>(&proj_b2[dd]);
  float2 hl = *reinterpret_cast<const float2*>(&h_lig[(size_t)l * 128 + dd]);
  float x0 = agg0 + gval * pb2.x + hl.x;
  float x1 = agg1 + gval * pb2.y + hl.y;
  float s = x0 + x1, q = x0 * x0 + x1 * x1;
  wave_sum2(s, q);
  float mu = s * (1.0f / 128.0f);
  float var = q * (1.0f / 128.0f) - mu * mu;
  float rstd = rsqrtf(var + 1e-5f);
  float2 gm = *reinterpret_cast<const float2*>(&ln_g[dd]);
  float2 bt = *reinterpret_cast<const float2*>(&ln_b[dd]);
  float2 y = make_float2((x0 - mu) * rstd * gm.x + bt.x,
                         (x1 - mu) * rstd * gm.y + bt.y);
  *reinterpret_cast<float2*>(&out[(size_t)(np_total + l) * 128 + dd]) = y;
}

extern "C" void kernel_launch(void* const* d_in, const int* in_sizes, int n_in,
                              void* d_out, int out_size, void* d_ws, size_t ws_size,
                              hipStream_t stream) {
  const float* h_prot   = (const float*)d_in[0];
  const float* h_lig    = (const float*)d_in[1];
  const float* prot_pos = (const float*)d_in[2];
  const float* lig_pos  = (const float*)d_in[3];
  const int*   edges    = (const int*)d_in[4];
  const float* att_w1   = (const float*)d_in[5];
  const float* att_b1   = (const float*)d_in[6];
  const float* att_w2   = (const float*)d_in[7];
  const float* att_b2   = (const float*)d_in[8];
  const float* proj_w1  = (const float*)d_in[9];
  const float* proj_b1  = (const float*)d_in[10];
  const float* proj_w2  = (const float*)d_in[11];
  const float* proj_b2  = (const float*)d_in[12];
  const float* ln_g     = (const float*)d_in[13];
  const float* ln_b     = (const float*)d_in[14];

  int NP = in_sizes[0] / 128;
  int NL = in_sizes[1] / 128;
  int NE = in_sizes[4] / 2;
  const int* p_idx = edges;
  const int* l_idx = edges + NE;

  float* out = (float*)d_out;

  // workspace layout
  float* PAPP = (float*)d_ws;                      // NP x 256, interleaved A/P
  float* LA = PAPP + (size_t)NP * 256;
  float* LP = LA + (size_t)NL * 128;
  float* Gq = LP + (size_t)NL * 128;               // 40 x 128 (k-paired layout)
  int* counts  = (int*)(Gq + 40 * 128);
  int* offsets = counts + NL;
  int* cursor  = offsets + NL;
  int* sorted_p = cursor + NL;

  (void)hipMemsetAsync(counts, 0, (size_t)NL * sizeof(int), stream);

  k_prep<<<2048, 256, 0, stream>>>((const float4*)h_prot, (float4*)out, NP * 128 / 4,
                                   att_w1, proj_w1, Gq, l_idx, NE, counts);

  k_tables<<<(NP + 7) / 8, 256, 0, stream>>>(h_prot, NP, att_w1, proj_w1,
                                             nullptr, nullptr, PAPP, nullptr, 1);
  k_tables<<<(NL + 7) / 8, 256, 0, stream>>>(h_lig, NL, att_w1 + 128 * 128,
                                             proj_w1 + 128 * 128, att_b1, proj_b1,
                                             LA, LP, 0);

  k_scan<<<1, 1024, 0, stream>>>(counts, offsets, cursor, NL);
  k_scatter<<<4096, 256, 0, stream>>>(p_idx, l_idx, NE, cursor, sorted_p);

  k_edge<<<NL, 64, 0, stream>>>(PAPP, Gq, LA, LP, prot_pos, lig_pos,
                                offsets, counts, sorted_p,
                                att_w2, att_b2, proj_w2, proj_b2,
                                h_lig, ln_g, ln_b, out, NP, NL);
}